// Round 9
// baseline (634.957 us; speedup 1.0000x reference)
//
#include <hip/hip_runtime.h>

#define BB 2
#define SS 2048
#define DM 1024
#define NH 16
#define DH 64
#define BP (BB*SS)            // 4096
#define BHSD (BB*NH*SS*DH)    // 4,194,304 elements

typedef __attribute__((ext_vector_type(8))) short short8v;   // 8 x bf16 (4 VGPR)
typedef __attribute__((ext_vector_type(4))) float float4v;   // MFMA C/D

// round-to-nearest-even fp32 -> bf16 (finite inputs)
__device__ __forceinline__ unsigned short f2bf(float f) {
    unsigned int u = __float_as_uint(f);
    u += 0x7fffu + ((u >> 16) & 1u);
    return (unsigned short)(u >> 16);
}

__device__ __forceinline__ short8v ld8(const unsigned short* p) {
    return *(const short8v*)p;
}

// async global->LDS, 16B per lane; LDS dest = wave-uniform base + lane*16
__device__ __forceinline__ void async_cp16(const void* g, void* l) {
    __builtin_amdgcn_global_load_lds(
        (const __attribute__((address_space(1))) unsigned int*)g,
        (__attribute__((address_space(3))) unsigned int*)l, 16, 0, 0);
}

// ---------------------------------------------------------------------------
// x (fp32 [4096][1024]) -> xb (bf16), vectorized 8/thread
// ---------------------------------------------------------------------------
__global__ __launch_bounds__(256) void k_cvtx(const float* __restrict__ x,
                                              unsigned short* __restrict__ xb) {
    const size_t i = (size_t)blockIdx.x * 256 + threadIdx.x;
    const float4 a = ((const float4*)x)[i * 2];
    const float4 b = ((const float4*)x)[i * 2 + 1];
    uint4 o;
    o.x = f2bf(a.x) | ((unsigned)f2bf(a.y) << 16);
    o.y = f2bf(a.z) | ((unsigned)f2bf(a.w) << 16);
    o.z = f2bf(b.x) | ((unsigned)f2bf(b.y) << 16);
    o.w = f2bf(b.z) | ((unsigned)f2bf(b.w) << 16);
    ((uint4*)xb)[i] = o;
}

// ---------------------------------------------------------------------------
// Weight repack: transpose+convert fp32 [1024][C] -> bf16 [C][1024].
// z<48: QKV head matrices (C=64) -> WbT rows (set*16+h)*64+dh.  z=48: O -> ObT.
// ---------------------------------------------------------------------------
__global__ __launch_bounds__(256) void k_wrepack(
    const float* __restrict__ Qs, const float* __restrict__ Ks,
    const float* __restrict__ Vs, const float* __restrict__ O,
    unsigned short* __restrict__ WbT, unsigned short* __restrict__ ObT)
{
    __shared__ float t[64][65];
    const int z = blockIdx.z;
    const float* src; unsigned short* dst; int C;
    if (z < 48) {
        if (blockIdx.y != 0) return;          // block-uniform early exit
        const int set = z >> 4, h = z & 15;
        src = ((set == 0) ? Qs : (set == 1) ? Ks : Vs) + (size_t)h * DM * DH;
        dst = WbT + (size_t)z * DH * DM;
        C = DH;
    } else { src = O; dst = ObT; C = DM; }
    const int r0 = blockIdx.x * 64, c0 = blockIdx.y * 64;
    const int tid = threadIdx.x, c = tid & 63, r4 = tid >> 6;
    #pragma unroll
    for (int i = 0; i < 16; ++i) {
        int r = r4 + i * 4;
        t[r][c] = src[(size_t)(r0 + r) * C + c0 + c];
    }
    __syncthreads();
    #pragma unroll
    for (int i = 0; i < 16; ++i) {
        int rr = r4 + i * 4;                  // source col within tile
        dst[(size_t)(c0 + rr) * DM + r0 + c] = f2bf(t[c][rr]);  // pad-65: conflict-free
    }
}

// ---------------------------------------------------------------------------
// bf16 transpose v [b][h][s][64] -> vT [b][h][64][s]
// ---------------------------------------------------------------------------
__global__ __launch_bounds__(256) void k_vt(const unsigned short* __restrict__ v,
                                            unsigned short* __restrict__ vT) {
    __shared__ unsigned short t[64][66];      // pad 66: col-read 2-way (free)
    const int bh = blockIdx.y;
    const int s0 = blockIdx.x * 64;
    const unsigned short* src = v + (size_t)bh * SS * DH + (size_t)s0 * DH;
    unsigned short* dst = vT + (size_t)bh * DH * SS + s0;
    const int tid = threadIdx.x, c = tid & 63, r4 = tid >> 6;
    #pragma unroll
    for (int i = 0; i < 16; ++i) { int r = r4 + i * 4; t[r][c] = src[r * DH + c]; }
    __syncthreads();
    #pragma unroll
    for (int i = 0; i < 16; ++i) { int dr = r4 + i * 4; dst[(size_t)dr * SS + c] = t[c][dr]; }
}

// ---------------------------------------------------------------------------
// bf16 MFMA GEMM, m97 structure: C[M][N] = A[M][K] * B[N][K]^T.
// 128x128 tile, BK=32, 4 waves (2x2), each wave 64x64 = 4x4 MFMA frags.
// MODE 0: qkv epilogue (bf16, scatter to [set][b][h][s][dh], +bias per set)
// MODE 1: fp32 row-major out, +bias
// ---------------------------------------------------------------------------
template<int MODE>
__global__ __launch_bounds__(256) void k_gemm(
    const unsigned short* __restrict__ A, const unsigned short* __restrict__ Bm,
    void* __restrict__ Cout, int N, int K,
    const float* __restrict__ bq, const float* __restrict__ bk,
    const float* __restrict__ bv)
{
    __shared__ __align__(16) unsigned short Al[128 * 32];   // [row][32k] linear, 64B rows
    __shared__ __align__(16) unsigned short Bl[128 * 32];
    const int tid = threadIdx.x;
    const int w = tid >> 6, l = tid & 63;
    const int ll = l & 15, lh = l >> 4;
    const int m0 = blockIdx.x * 128, n0 = blockIdx.y * 128;
    const int wm = w >> 1, wn = w & 1;
    const int sr = l >> 2, sc = l & 3;        // staging: lane -> (row, 16B-chunk)

    const float4v vzero = {0.f, 0.f, 0.f, 0.f};
    float4v acc[4][4];
    #pragma unroll
    for (int i = 0; i < 4; ++i)
        #pragma unroll
        for (int j = 0; j < 4; ++j) acc[i][j] = vzero;

    for (int k0 = 0; k0 < K; k0 += 32) {
        __syncthreads();                      // previous tile fully consumed
        #pragma unroll
        for (int half = 0; half < 2; ++half) {
            const int r = w * 32 + half * 16 + sr;
            async_cp16(A + (size_t)(m0 + r) * K + k0 + sc * 8,
                       &Al[(w * 32 + half * 16) * 32]);
            async_cp16(Bm + (size_t)(n0 + r) * K + k0 + sc * 8,
                       &Bl[(w * 32 + half * 16) * 32]);
        }
        __syncthreads();                      // compiler drains vmcnt before barrier

        short8v af[4], bfr[4];
        #pragma unroll
        for (int mi = 0; mi < 4; ++mi)
            af[mi] = *(const short8v*)&Al[(wm * 64 + mi * 16 + ll) * 32 + lh * 8];
        #pragma unroll
        for (int ni = 0; ni < 4; ++ni)
            bfr[ni] = *(const short8v*)&Bl[(wn * 64 + ni * 16 + ll) * 32 + lh * 8];
        #pragma unroll
        for (int mi = 0; mi < 4; ++mi)
            #pragma unroll
            for (int ni = 0; ni < 4; ++ni)
                acc[mi][ni] = __builtin_amdgcn_mfma_f32_16x16x32_bf16(
                    af[mi], bfr[ni], acc[mi][ni], 0, 0, 0);
    }

    // epilogue: C/D layout col=lane&15, row=(lane>>4)*4+reg  [m89-verified]
    #pragma unroll
    for (int mi = 0; mi < 4; ++mi)
        #pragma unroll
        for (int ni = 0; ni < 4; ++ni)
            #pragma unroll
            for (int r = 0; r < 4; ++r) {
                const int gm = m0 + wm * 64 + mi * 16 + lh * 4 + r;
                const int gn = n0 + wn * 64 + ni * 16 + ll;
                float val = acc[mi][ni][r];
                if (MODE == 0) {
                    const int set = gn >> 10, h = (gn >> 6) & 15, dh = gn & 63;
                    const float* bias = (set == 0) ? bq : (set == 1) ? bk : bv;
                    val += bias[(h << 6) + dh];
                    const int b_ = gm >> 11, s = gm & 2047;
                    ((unsigned short*)Cout)[(size_t)set * BHSD +
                        (((size_t)(b_ * NH + h) * SS + s) << 6) + dh] = f2bf(val);
                } else {
                    val += bq[gn];
                    ((float*)Cout)[(size_t)gm * N + gn] = val;
                }
            }
}

// ---------------------------------------------------------------------------
// Flash attention, bf16 MFMA, round-5 version:
//  - ONE WAVE PER BLOCK (64 thr): 4096 independent blocks (bh x qt x 4 strips)
//    -> scheduler backfills short causal blocks, ~4x time-avg waves/SIMD
//  - per-XCD dispatch order: qt descending across the XCD's 4 bh (heavy first,
//    K/V L2-resident), strips innermost
//  - depth-1 pipeline, deferred row-sum, s_setprio kept from round 4
// ---------------------------------------------------------------------------
__global__ __launch_bounds__(64, 6) void k_attn(
    const unsigned short* __restrict__ qg, const unsigned short* __restrict__ kg,
    const unsigned short* __restrict__ vtg, unsigned short* __restrict__ zg)
{
    __shared__ __align__(16) float Plds[16][68];
    const int l = threadIdx.x;
    const int ll = l & 15, lh = l >> 4;
    // bid -> (xcd | qt desc | bh_local | strip); HW: wgid%8 = XCD
    const unsigned bid = blockIdx.x;              // 0..4095
    const unsigned xcd = bid & 7, within = bid >> 3;      // within: 0..511
    const int qt = 31 - (int)(within >> 4);
    const unsigned rest = within & 15;
    const int bh = (int)((xcd << 2) | (rest >> 2));       // 4 bh per XCD
    const int strip = (int)(rest & 3);
    const int q0 = qt * 64 + strip * 16;
    const unsigned short* qb = qg + (size_t)bh * SS * DH;
    const unsigned short* kb = kg + (size_t)bh * SS * DH;
    const unsigned short* vb = vtg + (size_t)bh * DH * SS;

    short8v qf[2];      // A-frag: lane holds Q[row=ll][k=lh*8+j] (+32 for second)
    qf[0] = ld8(qb + (size_t)(q0 + ll) * DH + lh * 8);
    qf[1] = ld8(qb + (size_t)(q0 + ll) * DH + 32 + lh * 8);

    const float4v vzero = {0.f, 0.f, 0.f, 0.f};
    float4v zacc[4];
    #pragma unroll
    for (int n = 0; n < 4; ++n) zacc[n] = vzero;
    float mrow[4] = {-1e30f, -1e30f, -1e30f, -1e30f};
    float lrow[4] = {0.f, 0.f, 0.f, 0.f};     // lane-PARTIAL sums (deferred reduce)

    // preload K fragments for jt=0
    short8v kf[8];
    #pragma unroll
    for (int n = 0; n < 4; ++n) {
        kf[n * 2]     = ld8(kb + (size_t)(n * 16 + ll) * DH + lh * 8);
        kf[n * 2 + 1] = ld8(kb + (size_t)(n * 16 + ll) * DH + 32 + lh * 8);
    }

    for (int jt = 0; jt <= qt; ++jt) {
        // ---- issue current-V loads + next-K prefetch EARLY (hide under softmax)
        const unsigned short* vt = vb + jt * 64;
        short8v vf[8];
        #pragma unroll
        for (int n = 0; n < 4; ++n) {
            vf[n * 2]     = ld8(vt + (size_t)(n * 16 + ll) * SS + lh * 8);
            vf[n * 2 + 1] = ld8(vt + (size_t)(n * 16 + ll) * SS + 32 + lh * 8);
        }
        const int jn = (jt < qt) ? jt + 1 : jt;   // clamped (redundant last iter)
        const unsigned short* ktn = kb + (size_t)jn * 64 * DH;
        short8v nkf[8];
        #pragma unroll
        for (int n = 0; n < 4; ++n) {
            nkf[n * 2]     = ld8(ktn + (size_t)(n * 16 + ll) * DH + lh * 8);
            nkf[n * 2 + 1] = ld8(ktn + (size_t)(n * 16 + ll) * DH + 32 + lh * 8);
        }

        // ---- S = Q K^T / 8 ----
        float4v sv[4];
        __builtin_amdgcn_s_setprio(1);
        #pragma unroll
        for (int n = 0; n < 4; ++n) {
            float4v t = vzero;
            t = __builtin_amdgcn_mfma_f32_16x16x32_bf16(qf[0], kf[n * 2], t, 0, 0, 0);
            t = __builtin_amdgcn_mfma_f32_16x16x32_bf16(qf[1], kf[n * 2 + 1], t, 0, 0, 0);
            sv[n] = t;
        }
        __builtin_amdgcn_s_setprio(0);

        const bool diag = (jt == qt);
        #pragma unroll
        for (int n = 0; n < 4; ++n)
            #pragma unroll
            for (int r = 0; r < 4; ++r) {
                float xv = sv[n][r] * 0.125f;
                if (diag && (jt * 64 + n * 16 + ll) > (q0 + lh * 4 + r)) xv = -1e30f;
                sv[n][r] = xv;
            }

        // ---- online softmax: exact running max; lane-partial sum (no sum shfl)
        #pragma unroll
        for (int r = 0; r < 4; ++r) {
            float mx = fmaxf(fmaxf(sv[0][r], sv[1][r]), fmaxf(sv[2][r], sv[3][r]));
            #pragma unroll
            for (int o = 1; o < 16; o <<= 1) mx = fmaxf(mx, __shfl_xor(mx, o, 64));
            const float mn = fmaxf(mrow[r], mx);
            const float corr = __expf(mrow[r] - mn);
            mrow[r] = mn;
            float ps = 0.f;
            #pragma unroll
            for (int n = 0; n < 4; ++n) {
                const float p = __expf(sv[n][r] - mn);
                sv[n][r] = p; ps += p;
            }
            lrow[r] = lrow[r] * corr + ps;    // lane-partial; reduced at epilogue
            #pragma unroll
            for (int n = 0; n < 4; ++n) zacc[n][r] *= corr;
            #pragma unroll
            for (int n = 0; n < 4; ++n) Plds[lh * 4 + r][n * 16 + ll] = sv[n][r];
        }

        // ---- P (C-layout) -> A-frags via wave-private LDS; cvt to bf16 ----
        short8v pa[2];
        #pragma unroll
        for (int kk = 0; kk < 2; ++kk)
            #pragma unroll
            for (int j = 0; j < 8; ++j)
                pa[kk][j] = (short)f2bf(Plds[ll][kk * 32 + lh * 8 + j]);

        // ---- z += P @ V  (V-frags already in registers) ----
        __builtin_amdgcn_s_setprio(1);
        #pragma unroll
        for (int n = 0; n < 4; ++n) {
            zacc[n] = __builtin_amdgcn_mfma_f32_16x16x32_bf16(pa[0], vf[n * 2], zacc[n], 0, 0, 0);
            zacc[n] = __builtin_amdgcn_mfma_f32_16x16x32_bf16(pa[1], vf[n * 2 + 1], zacc[n], 0, 0, 0);
        }
        __builtin_amdgcn_s_setprio(0);

        #pragma unroll
        for (int t = 0; t < 8; ++t) kf[t] = nkf[t];
    }

    // ---- deferred sum-reduce (once per block) + epilogue ----
    float inv[4];
    #pragma unroll
    for (int r = 0; r < 4; ++r) {
        float s = lrow[r];
        #pragma unroll
        for (int o = 1; o < 16; o <<= 1) s += __shfl_xor(s, o, 64);
        inv[r] = 1.f / s;
    }
    const int b_ = bh >> 4, h = bh & 15;
    #pragma unroll
    for (int n = 0; n < 4; ++n)
        #pragma unroll
        for (int r = 0; r < 4; ++r) {
            const int s = q0 + lh * 4 + r;
            zg[(((size_t)(b_ * SS + s)) << 10) + (h << 6) + n * 16 + ll] =
                f2bf(zacc[n][r] * inv[r]);
        }
}

// ---------------------------------------------------------------------------
extern "C" void kernel_launch(void* const* d_in, const int* in_sizes, int n_in,
                              void* d_out, int out_size, void* d_ws, size_t ws_size,
                              hipStream_t stream)
{
    const float* x   = (const float*)d_in[0];
    const float* Qs  = (const float*)d_in[1];
    const float* Qbs = (const float*)d_in[2];
    const float* Ks  = (const float*)d_in[3];
    const float* Kbs = (const float*)d_in[4];
    const float* Vs  = (const float*)d_in[5];
    const float* Vbs = (const float*)d_in[6];
    const float* O   = (const float*)d_in[7];
    const float* Ob  = (const float*)d_in[8];

    unsigned short* xb  = (unsigned short*)d_ws;          // [4096][1024]
    unsigned short* WbT = xb  + (size_t)BP * DM;          // [3072][1024]
    unsigned short* ObT = WbT + (size_t)3 * NH * DH * DM; // [1024][1024]
    unsigned short* qkv = ObT + (size_t)DM * DM;          // 3 x [b][h][s][dh]
    unsigned short* vT  = qkv + (size_t)3 * BHSD;         // [b][h][dh][s]
    unsigned short* z   = vT  + (size_t)BHSD;             // [4096][1024]

    k_cvtx<<<dim3(BP * DM / 2048), 256, 0, stream>>>(x, xb);
    k_wrepack<<<dim3(16, 16, 49), 256, 0, stream>>>(Qs, Ks, Vs, O, WbT, ObT);
    k_gemm<0><<<dim3(BP / 128, 3 * DM / 128), 256, 0, stream>>>(
        xb, WbT, qkv, 3 * DM, DM, Qbs, Kbs, Vbs);
    k_vt<<<dim3(SS / 64, BB * NH), 256, 0, stream>>>(qkv + (size_t)2 * BHSD, vT);
    k_attn<<<dim3(SS / 64 * BB * NH * 4), 64, 0, stream>>>(qkv, qkv + BHSD, vT, z);
    k_gemm<1><<<dim3(BP / 128, DM / 128), 256, 0, stream>>>(
        z, ObT, d_out, DM, DM, Ob, nullptr, nullptr);
}

// Round 10
// 354.392 us; speedup vs baseline: 1.7917x; 1.7917x over previous
//
#include <hip/hip_runtime.h>

#define BB 2
#define SS 2048
#define DM 1024
#define NH 16
#define DH 64
#define BP (BB*SS)            // 4096
#define BHSD (BB*NH*SS*DH)    // 4,194,304 elements

typedef __attribute__((ext_vector_type(8))) short short8v;   // 8 x bf16 (4 VGPR)
typedef __attribute__((ext_vector_type(4))) float float4v;   // MFMA C/D

// round-to-nearest-even fp32 -> bf16 (finite inputs)
__device__ __forceinline__ unsigned short f2bf(float f) {
    unsigned int u = __float_as_uint(f);
    u += 0x7fffu + ((u >> 16) & 1u);
    return (unsigned short)(u >> 16);
}

__device__ __forceinline__ short8v ld8(const unsigned short* p) {
    return *(const short8v*)p;
}

// async global->LDS, 16B per lane; LDS dest = wave-uniform base + lane*16
__device__ __forceinline__ void async_cp16(const void* g, void* l) {
    __builtin_amdgcn_global_load_lds(
        (const __attribute__((address_space(1))) unsigned int*)g,
        (__attribute__((address_space(3))) unsigned int*)l, 16, 0, 0);
}

// ---------------------------------------------------------------------------
// x (fp32 [4096][1024]) -> xb (bf16), vectorized 8/thread
// ---------------------------------------------------------------------------
__global__ __launch_bounds__(256) void k_cvtx(const float* __restrict__ x,
                                              unsigned short* __restrict__ xb) {
    const size_t i = (size_t)blockIdx.x * 256 + threadIdx.x;
    const float4 a = ((const float4*)x)[i * 2];
    const float4 b = ((const float4*)x)[i * 2 + 1];
    uint4 o;
    o.x = f2bf(a.x) | ((unsigned)f2bf(a.y) << 16);
    o.y = f2bf(a.z) | ((unsigned)f2bf(a.w) << 16);
    o.z = f2bf(b.x) | ((unsigned)f2bf(b.y) << 16);
    o.w = f2bf(b.z) | ((unsigned)f2bf(b.w) << 16);
    ((uint4*)xb)[i] = o;
}

// ---------------------------------------------------------------------------
// Weight repack: transpose+convert fp32 [1024][C] -> bf16 [C][1024].
// z<48: QKV head matrices (C=64) -> WbT rows (set*16+h)*64+dh.  z=48: O -> ObT.
// ---------------------------------------------------------------------------
__global__ __launch_bounds__(256) void k_wrepack(
    const float* __restrict__ Qs, const float* __restrict__ Ks,
    const float* __restrict__ Vs, const float* __restrict__ O,
    unsigned short* __restrict__ WbT, unsigned short* __restrict__ ObT)
{
    __shared__ float t[64][65];
    const int z = blockIdx.z;
    const float* src; unsigned short* dst; int C;
    if (z < 48) {
        if (blockIdx.y != 0) return;          // block-uniform early exit
        const int set = z >> 4, h = z & 15;
        src = ((set == 0) ? Qs : (set == 1) ? Ks : Vs) + (size_t)h * DM * DH;
        dst = WbT + (size_t)z * DH * DM;
        C = DH;
    } else { src = O; dst = ObT; C = DM; }
    const int r0 = blockIdx.x * 64, c0 = blockIdx.y * 64;
    const int tid = threadIdx.x, c = tid & 63, r4 = tid >> 6;
    #pragma unroll
    for (int i = 0; i < 16; ++i) {
        int r = r4 + i * 4;
        t[r][c] = src[(size_t)(r0 + r) * C + c0 + c];
    }
    __syncthreads();
    #pragma unroll
    for (int i = 0; i < 16; ++i) {
        int rr = r4 + i * 4;                  // source col within tile
        dst[(size_t)(c0 + rr) * DM + r0 + c] = f2bf(t[c][rr]);  // pad-65: conflict-free
    }
}

// ---------------------------------------------------------------------------
// bf16 transpose v [b][h][s][64] -> vT [b][h][64][s]
// ---------------------------------------------------------------------------
__global__ __launch_bounds__(256) void k_vt(const unsigned short* __restrict__ v,
                                            unsigned short* __restrict__ vT) {
    __shared__ unsigned short t[64][66];      // pad 66: col-read 2-way (free)
    const int bh = blockIdx.y;
    const int s0 = blockIdx.x * 64;
    const unsigned short* src = v + (size_t)bh * SS * DH + (size_t)s0 * DH;
    unsigned short* dst = vT + (size_t)bh * DH * SS + s0;
    const int tid = threadIdx.x, c = tid & 63, r4 = tid >> 6;
    #pragma unroll
    for (int i = 0; i < 16; ++i) { int r = r4 + i * 4; t[r][c] = src[r * DH + c]; }
    __syncthreads();
    #pragma unroll
    for (int i = 0; i < 16; ++i) { int dr = r4 + i * 4; dst[(size_t)dr * SS + c] = t[c][dr]; }
}

// ---------------------------------------------------------------------------
// bf16 MFMA GEMM, m97 structure: C[M][N] = A[M][K] * B[N][K]^T.
// 128x128 tile, BK=32, 4 waves (2x2), each wave 64x64 = 4x4 MFMA frags.
// MODE 0: qkv epilogue (bf16, scatter to [set][b][h][s][dh], +bias per set)
// MODE 1: fp32 row-major out, +bias
// ---------------------------------------------------------------------------
template<int MODE>
__global__ __launch_bounds__(256) void k_gemm(
    const unsigned short* __restrict__ A, const unsigned short* __restrict__ Bm,
    void* __restrict__ Cout, int N, int K,
    const float* __restrict__ bq, const float* __restrict__ bk,
    const float* __restrict__ bv)
{
    __shared__ __align__(16) unsigned short Al[128 * 32];   // [row][32k] linear, 64B rows
    __shared__ __align__(16) unsigned short Bl[128 * 32];
    const int tid = threadIdx.x;
    const int w = tid >> 6, l = tid & 63;
    const int ll = l & 15, lh = l >> 4;
    const int m0 = blockIdx.x * 128, n0 = blockIdx.y * 128;
    const int wm = w >> 1, wn = w & 1;
    const int sr = l >> 2, sc = l & 3;        // staging: lane -> (row, 16B-chunk)

    const float4v vzero = {0.f, 0.f, 0.f, 0.f};
    float4v acc[4][4];
    #pragma unroll
    for (int i = 0; i < 4; ++i)
        #pragma unroll
        for (int j = 0; j < 4; ++j) acc[i][j] = vzero;

    for (int k0 = 0; k0 < K; k0 += 32) {
        __syncthreads();                      // previous tile fully consumed
        #pragma unroll
        for (int half = 0; half < 2; ++half) {
            const int r = w * 32 + half * 16 + sr;
            async_cp16(A + (size_t)(m0 + r) * K + k0 + sc * 8,
                       &Al[(w * 32 + half * 16) * 32]);
            async_cp16(Bm + (size_t)(n0 + r) * K + k0 + sc * 8,
                       &Bl[(w * 32 + half * 16) * 32]);
        }
        __syncthreads();                      // compiler drains vmcnt before barrier

        short8v af[4], bfr[4];
        #pragma unroll
        for (int mi = 0; mi < 4; ++mi)
            af[mi] = *(const short8v*)&Al[(wm * 64 + mi * 16 + ll) * 32 + lh * 8];
        #pragma unroll
        for (int ni = 0; ni < 4; ++ni)
            bfr[ni] = *(const short8v*)&Bl[(wn * 64 + ni * 16 + ll) * 32 + lh * 8];
        #pragma unroll
        for (int mi = 0; mi < 4; ++mi)
            #pragma unroll
            for (int ni = 0; ni < 4; ++ni)
                acc[mi][ni] = __builtin_amdgcn_mfma_f32_16x16x32_bf16(
                    af[mi], bfr[ni], acc[mi][ni], 0, 0, 0);
    }

    // epilogue: C/D layout col=lane&15, row=(lane>>4)*4+reg  [m89-verified]
    #pragma unroll
    for (int mi = 0; mi < 4; ++mi)
        #pragma unroll
        for (int ni = 0; ni < 4; ++ni)
            #pragma unroll
            for (int r = 0; r < 4; ++r) {
                const int gm = m0 + wm * 64 + mi * 16 + lh * 4 + r;
                const int gn = n0 + wn * 64 + ni * 16 + ll;
                float val = acc[mi][ni][r];
                if (MODE == 0) {
                    const int set = gn >> 10, h = (gn >> 6) & 15, dh = gn & 63;
                    const float* bias = (set == 0) ? bq : (set == 1) ? bk : bv;
                    val += bias[(h << 6) + dh];
                    const int b_ = gm >> 11, s = gm & 2047;
                    ((unsigned short*)Cout)[(size_t)set * BHSD +
                        (((size_t)(b_ * NH + h) * SS + s) << 6) + dh] = f2bf(val);
                } else {
                    val += bq[gn];
                    ((float*)Cout)[(size_t)gm * N + gn] = val;
                }
            }
}

// ---------------------------------------------------------------------------
// Flash attention, bf16 MFMA, round-8 version:
//  - ONE WAVE PER BLOCK (64 thr), 4096 blocks — unchanged from round 5
//  - FIX vs round 5: __launch_bounds__(64,4) (VGPR cap 128, was 85).
//    The 85-cap forced the allocator to spill kf/nkf/vf arrays to scratch
//    (VGPR 40, WRITE_SIZE 1.14 GB, 2.3x regression). Cap 128 restores the
//    round-4-proven ~84-VGPR allocation; occupancy then = 512/VGPR ~ 5-6
//    waves/SIMD via the 1-wave backfill scheduler.
// ---------------------------------------------------------------------------
__global__ __launch_bounds__(64, 4) void k_attn(
    const unsigned short* __restrict__ qg, const unsigned short* __restrict__ kg,
    const unsigned short* __restrict__ vtg, unsigned short* __restrict__ zg)
{
    __shared__ __align__(16) float Plds[16][68];
    const int l = threadIdx.x;
    const int ll = l & 15, lh = l >> 4;
    // bid -> (xcd | qt desc | bh_local | strip); HW: wgid%8 = XCD
    const unsigned bid = blockIdx.x;              // 0..4095
    const unsigned xcd = bid & 7, within = bid >> 3;      // within: 0..511
    const int qt = 31 - (int)(within >> 4);
    const unsigned rest = within & 15;
    const int bh = (int)((xcd << 2) | (rest >> 2));       // 4 bh per XCD
    const int strip = (int)(rest & 3);
    const int q0 = qt * 64 + strip * 16;
    const unsigned short* qb = qg + (size_t)bh * SS * DH;
    const unsigned short* kb = kg + (size_t)bh * SS * DH;
    const unsigned short* vb = vtg + (size_t)bh * DH * SS;

    short8v qf[2];      // A-frag: lane holds Q[row=ll][k=lh*8+j] (+32 for second)
    qf[0] = ld8(qb + (size_t)(q0 + ll) * DH + lh * 8);
    qf[1] = ld8(qb + (size_t)(q0 + ll) * DH + 32 + lh * 8);

    const float4v vzero = {0.f, 0.f, 0.f, 0.f};
    float4v zacc[4];
    #pragma unroll
    for (int n = 0; n < 4; ++n) zacc[n] = vzero;
    float mrow[4] = {-1e30f, -1e30f, -1e30f, -1e30f};
    float lrow[4] = {0.f, 0.f, 0.f, 0.f};     // lane-PARTIAL sums (deferred reduce)

    // preload K fragments for jt=0
    short8v kf[8];
    #pragma unroll
    for (int n = 0; n < 4; ++n) {
        kf[n * 2]     = ld8(kb + (size_t)(n * 16 + ll) * DH + lh * 8);
        kf[n * 2 + 1] = ld8(kb + (size_t)(n * 16 + ll) * DH + 32 + lh * 8);
    }

    for (int jt = 0; jt <= qt; ++jt) {
        // ---- issue current-V loads + next-K prefetch EARLY (hide under softmax)
        const unsigned short* vt = vb + jt * 64;
        short8v vf[8];
        #pragma unroll
        for (int n = 0; n < 4; ++n) {
            vf[n * 2]     = ld8(vt + (size_t)(n * 16 + ll) * SS + lh * 8);
            vf[n * 2 + 1] = ld8(vt + (size_t)(n * 16 + ll) * SS + 32 + lh * 8);
        }
        const int jn = (jt < qt) ? jt + 1 : jt;   // clamped (redundant last iter)
        const unsigned short* ktn = kb + (size_t)jn * 64 * DH;
        short8v nkf[8];
        #pragma unroll
        for (int n = 0; n < 4; ++n) {
            nkf[n * 2]     = ld8(ktn + (size_t)(n * 16 + ll) * DH + lh * 8);
            nkf[n * 2 + 1] = ld8(ktn + (size_t)(n * 16 + ll) * DH + 32 + lh * 8);
        }

        // ---- S = Q K^T / 8 ----
        float4v sv[4];
        __builtin_amdgcn_s_setprio(1);
        #pragma unroll
        for (int n = 0; n < 4; ++n) {
            float4v t = vzero;
            t = __builtin_amdgcn_mfma_f32_16x16x32_bf16(qf[0], kf[n * 2], t, 0, 0, 0);
            t = __builtin_amdgcn_mfma_f32_16x16x32_bf16(qf[1], kf[n * 2 + 1], t, 0, 0, 0);
            sv[n] = t;
        }
        __builtin_amdgcn_s_setprio(0);

        const bool diag = (jt == qt);
        #pragma unroll
        for (int n = 0; n < 4; ++n)
            #pragma unroll
            for (int r = 0; r < 4; ++r) {
                float xv = sv[n][r] * 0.125f;
                if (diag && (jt * 64 + n * 16 + ll) > (q0 + lh * 4 + r)) xv = -1e30f;
                sv[n][r] = xv;
            }

        // ---- online softmax: exact running max; lane-partial sum (no sum shfl)
        #pragma unroll
        for (int r = 0; r < 4; ++r) {
            float mx = fmaxf(fmaxf(sv[0][r], sv[1][r]), fmaxf(sv[2][r], sv[3][r]));
            #pragma unroll
            for (int o = 1; o < 16; o <<= 1) mx = fmaxf(mx, __shfl_xor(mx, o, 64));
            const float mn = fmaxf(mrow[r], mx);
            const float corr = __expf(mrow[r] - mn);
            mrow[r] = mn;
            float ps = 0.f;
            #pragma unroll
            for (int n = 0; n < 4; ++n) {
                const float p = __expf(sv[n][r] - mn);
                sv[n][r] = p; ps += p;
            }
            lrow[r] = lrow[r] * corr + ps;    // lane-partial; reduced at epilogue
            #pragma unroll
            for (int n = 0; n < 4; ++n) zacc[n][r] *= corr;
            #pragma unroll
            for (int n = 0; n < 4; ++n) Plds[lh * 4 + r][n * 16 + ll] = sv[n][r];
        }

        // ---- P (C-layout) -> A-frags via wave-private LDS; cvt to bf16 ----
        short8v pa[2];
        #pragma unroll
        for (int kk = 0; kk < 2; ++kk)
            #pragma unroll
            for (int j = 0; j < 8; ++j)
                pa[kk][j] = (short)f2bf(Plds[ll][kk * 32 + lh * 8 + j]);

        // ---- z += P @ V  (V-frags already in registers) ----
        __builtin_amdgcn_s_setprio(1);
        #pragma unroll
        for (int n = 0; n < 4; ++n) {
            zacc[n] = __builtin_amdgcn_mfma_f32_16x16x32_bf16(pa[0], vf[n * 2], zacc[n], 0, 0, 0);
            zacc[n] = __builtin_amdgcn_mfma_f32_16x16x32_bf16(pa[1], vf[n * 2 + 1], zacc[n], 0, 0, 0);
        }
        __builtin_amdgcn_s_setprio(0);

        #pragma unroll
        for (int t = 0; t < 8; ++t) kf[t] = nkf[t];
    }

    // ---- deferred sum-reduce (once per block) + epilogue ----
    float inv[4];
    #pragma unroll
    for (int r = 0; r < 4; ++r) {
        float s = lrow[r];
        #pragma unroll
        for (int o = 1; o < 16; o <<= 1) s += __shfl_xor(s, o, 64);
        inv[r] = 1.f / s;
    }
    const int b_ = bh >> 4, h = bh & 15;
    #pragma unroll
    for (int n = 0; n < 4; ++n)
        #pragma unroll
        for (int r = 0; r < 4; ++r) {
            const int s = q0 + lh * 4 + r;
            zg[(((size_t)(b_ * SS + s)) << 10) + (h << 6) + n * 16 + ll] =
                f2bf(zacc[n][r] * inv[r]);
        }
}

// ---------------------------------------------------------------------------
extern "C" void kernel_launch(void* const* d_in, const int* in_sizes, int n_in,
                              void* d_out, int out_size, void* d_ws, size_t ws_size,
                              hipStream_t stream)
{
    const float* x   = (const float*)d_in[0];
    const float* Qs  = (const float*)d_in[1];
    const float* Qbs = (const float*)d_in[2];
    const float* Ks  = (const float*)d_in[3];
    const float* Kbs = (const float*)d_in[4];
    const float* Vs  = (const float*)d_in[5];
    const float* Vbs = (const float*)d_in[6];
    const float* O   = (const float*)d_in[7];
    const float* Ob  = (const float*)d_in[8];

    unsigned short* xb  = (unsigned short*)d_ws;          // [4096][1024]
    unsigned short* WbT = xb  + (size_t)BP * DM;          // [3072][1024]
    unsigned short* ObT = WbT + (size_t)3 * NH * DH * DM; // [1024][1024]
    unsigned short* qkv = ObT + (size_t)DM * DM;          // 3 x [b][h][s][dh]
    unsigned short* vT  = qkv + (size_t)3 * BHSD;         // [b][h][dh][s]
    unsigned short* z   = vT  + (size_t)BHSD;             // [4096][1024]

    k_cvtx<<<dim3(BP * DM / 2048), 256, 0, stream>>>(x, xb);
    k_wrepack<<<dim3(16, 16, 49), 256, 0, stream>>>(Qs, Ks, Vs, O, WbT, ObT);
    k_gemm<0><<<dim3(BP / 128, 3 * DM / 128), 256, 0, stream>>>(
        xb, WbT, qkv, 3 * DM, DM, Qbs, Kbs, Vbs);
    k_vt<<<dim3(SS / 64, BB * NH), 256, 0, stream>>>(qkv + (size_t)2 * BHSD, vT);
    k_attn<<<dim3(SS / 64 * BB * NH * 4), 64, 0, stream>>>(qkv, qkv + BHSD, vT, z);
    k_gemm<1><<<dim3(BP / 128, DM / 128), 256, 0, stream>>>(
        z, ObT, d_out, DM, DM, Ob, nullptr, nullptr);
}